// Round 1
// baseline (25080.255 us; speedup 1.0000x reference)
//
#include <hip/hip_runtime.h>

#define B_ 64
#define T_ 512
#define E_ 512
#define H_ 1024
#define C_ 20
#define NBLK 256

typedef __attribute__((ext_vector_type(8))) __bf16 bf16x8;
typedef __attribute__((ext_vector_type(4))) float f32x4;

__device__ __forceinline__ short f2bf(float x){
  unsigned u = __float_as_uint(x);
  unsigned r = (u + 0x7fffu + ((u >> 16) & 1u)) >> 16;   // RNE
  return (short)r;
}
__device__ __forceinline__ float bf2f(short s){
  return __uint_as_float(((unsigned)(unsigned short)s) << 16);
}

// ---------------------------------------------------------------------------
// Prep: W -> hi/lo bf16 splits, x -> bf16 (optional), zero h0 + barrier ctrs.
// Counters MUST be re-zeroed every launch (ws not re-poisoned between replays).
// ---------------------------------------------------------------------------
__global__ void prep_kernel(const float* __restrict__ x,
                            const float* __restrict__ wih,
                            const float* __restrict__ whh,
                            short* __restrict__ whhh, short* __restrict__ whhl,
                            short* __restrict__ wihh, short* __restrict__ wihl,
                            short* __restrict__ h0,
                            unsigned* __restrict__ ctrs,
                            short* __restrict__ xb)
{
  const long NH  = (long)H_ * H_;
  const long NI  = (long)H_ * E_;
  const long NH0 = (long)B_ * H_;
  const long NC  = 17L * T_;                 // ctr1[8T] + ctr2[T] + gflag[8T]
  const long NX  = xb ? (long)B_ * T_ * E_ : 0;
  const long TOT = NH + NI + NH0 + NC + NX;
  long i = (long)blockIdx.x * blockDim.x + threadIdx.x;
  const long stride = (long)gridDim.x * blockDim.x;
  for (; i < TOT; i += stride){
    if (i < NH){
      float v = whh[i]; short hi = f2bf(v);
      whhh[i] = hi; whhl[i] = f2bf(v - bf2f(hi));
    } else if (i < NH + NI){
      long j = i - NH; float v = wih[j]; short hi = f2bf(v);
      wihh[j] = hi; wihl[j] = f2bf(v - bf2f(hi));
    } else if (i < NH + NI + NH0){
      h0[i - NH - NI] = 0;
    } else if (i < NH + NI + NH0 + NC){
      ctrs[i - NH - NI - NH0] = 0u;
    } else {
      long j = i - NH - NI - NH0 - NC;
      xb[j] = f2bf(x[j]);
    }
  }
}

// ---------------------------------------------------------------------------
// Persistent scan kernel. 256 blocks = 4 batch-groups x 64 col-groups.
// Block tile: C[16 batches x 16 cols]; K=1024 split across 4 waves (256 each).
// W_hh / W_ih fragments live in VGPRs for the whole kernel (hi+lo bf16 split).
// One two-level device barrier per timestep; input projection for step t+1 is
// computed between barrier-arrive and barrier-wait to hide sync latency.
// ---------------------------------------------------------------------------
__global__ __launch_bounds__(256, 2) void rnn_scan(
    const float* __restrict__ x, const short* __restrict__ xb,
    const short* __restrict__ wihh, const short* __restrict__ wihl,
    const short* __restrict__ whhh, const short* __restrict__ whhl,
    const float* __restrict__ bih, const float* __restrict__ bhh,
    short* __restrict__ hb0, short* __restrict__ hb1,
    float* __restrict__ hT, unsigned* __restrict__ ctrs)
{
  unsigned* ctr1  = ctrs;             // [8][T]  per-group arrivals (ctr1[grp*T+t])
  unsigned* ctr2  = ctrs + 8 * T_;    // [T]     root counter
  unsigned* gflag = ctrs + 9 * T_;    // [8][T]  per-group go flags

  const int tid  = threadIdx.x;
  const int lane = tid & 63;
  const int wv   = tid >> 6;          // wave 0..3 -> K quarter
  const int bg   = blockIdx.x >> 6;   // batch group 0..3
  const int cg   = blockIdx.x & 63;   // col group 0..63
  const int grp  = blockIdx.x & 7;    // barrier group (XCD round-robin aligned)
  const int r16  = lane & 15;
  const int kq   = lane >> 4;         // 0..3

  __shared__ float redbuf[4 * 256];

  const int colRow = cg * 16 + r16;   // output col == W row
  const int hrow   = bg * 16 + r16;   // batch row

  // --- register-resident weight fragments (B-operand: lane l holds W[col=l&15][k0+(l>>4)*8 + i]) ---
  bf16x8 whhHi[8], whhLo[8];
  #pragma unroll
  for (int c = 0; c < 8; c++){
    int k0 = wv * 256 + c * 32 + kq * 8;
    whhHi[c] = *(const bf16x8*)(whhh + (long)colRow * H_ + k0);
    whhLo[c] = *(const bf16x8*)(whhl + (long)colRow * H_ + k0);
  }
  bf16x8 wihHi[4], wihLo[4];
  #pragma unroll
  for (int c = 0; c < 4; c++){
    int k0 = wv * 128 + c * 32 + kq * 8;
    wihHi[c] = *(const bf16x8*)(wihh + (long)colRow * E_ + k0);
    wihLo[c] = *(const bf16x8*)(wihl + (long)colRow * E_ + k0);
  }
  const float bias = bih[colRow] + bhh[colRow];

  auto load_xa = [&](int tn, int c) -> bf16x8 {
    int k0 = wv * 128 + c * 32 + kq * 8;
    if (xb){
      return *(const bf16x8*)(xb + ((long)hrow * T_ + tn) * E_ + k0);
    } else {
      const float* xp = x + ((long)hrow * T_ + tn) * E_ + k0;
      float4 f0 = *(const float4*)xp;
      float4 f1 = *(const float4*)(xp + 4);
      union { short s[8]; bf16x8 v; } u;
      u.s[0]=f2bf(f0.x); u.s[1]=f2bf(f0.y); u.s[2]=f2bf(f0.z); u.s[3]=f2bf(f0.w);
      u.s[4]=f2bf(f1.x); u.s[5]=f2bf(f1.y); u.s[6]=f2bf(f1.z); u.s[7]=f2bf(f1.w);
      return u.v;
    }
  };

  // input projection for t=0 (wave 0 seeds the bias so it is added exactly once)
  f32x4 xq;
  {
    float b0 = (wv == 0) ? bias : 0.f;
    f32x4 a = { b0, b0, b0, b0 };
    #pragma unroll
    for (int c = 0; c < 4; c++){
      bf16x8 xa = load_xa(0, c);
      a = __builtin_amdgcn_mfma_f32_16x16x32_bf16(xa, wihHi[c], a, 0, 0, 0);
      a = __builtin_amdgcn_mfma_f32_16x16x32_bf16(xa, wihLo[c], a, 0, 0, 0);
    }
    xq = a;
  }

  for (int t = 0; t < T_; ++t){
    const short* hbr = (t & 1) ? hb1 : hb0;
    short*       hbw = (t & 1) ? hb0 : hb1;

    // ---- recurrent GEMM: acc = xq_t + h_t @ W_hh^T (this wave's K quarter) ----
    f32x4 acc = xq;
    bf16x8 ha[8];
    #pragma unroll
    for (int c = 0; c < 8; c++){
      int k0 = wv * 256 + c * 32 + kq * 8;
      ha[c] = *(const bf16x8*)(hbr + (long)hrow * H_ + k0);
    }
    #pragma unroll
    for (int c = 0; c < 8; c++){
      acc = __builtin_amdgcn_mfma_f32_16x16x32_bf16(ha[c], whhHi[c], acc, 0, 0, 0);
      acc = __builtin_amdgcn_mfma_f32_16x16x32_bf16(ha[c], whhLo[c], acc, 0, 0, 0);
    }

    // ---- cross-wave K-reduction in LDS; C-frag: col=lane&15, row=(lane>>4)*4+i ----
    #pragma unroll
    for (int i = 0; i < 4; i++)
      redbuf[wv * 256 + (kq * 4 + i) * 16 + r16] = acc[i];
    __syncthreads();
    {
      int row = tid >> 4, col = tid & 15;
      int e = row * 16 + col;
      float s = redbuf[e] + redbuf[256 + e] + redbuf[512 + e] + redbuf[768 + e];
      float hv = tanhf(s);
      int gi = (bg * 16 + row) * H_ + cg * 16 + col;
      hbw[gi] = f2bf(hv);
      if (t == T_ - 1) hT[gi] = hv;
    }
    __threadfence();          // release: make h stores device-visible (wbL2)
    __syncthreads();          // everyone's stores+fence done before signaling

    // ---- barrier arrive (two-level) ----
    if (tid == 0){
      unsigned old = __hip_atomic_fetch_add(&ctr1[grp * T_ + t], 1u,
                                            __ATOMIC_ACQ_REL, __HIP_MEMORY_SCOPE_AGENT);
      if (old == 31u)
        __hip_atomic_fetch_add(&ctr2[t], 1u,
                               __ATOMIC_ACQ_REL, __HIP_MEMORY_SCOPE_AGENT);
    }

    // ---- overlap: input projection for t+1 while the barrier settles ----
    int tn = t + 1;
    if (tn < T_){
      float b0 = (wv == 0) ? bias : 0.f;
      f32x4 a = { b0, b0, b0, b0 };
      #pragma unroll
      for (int c = 0; c < 4; c++){
        bf16x8 xa = load_xa(tn, c);
        a = __builtin_amdgcn_mfma_f32_16x16x32_bf16(xa, wihHi[c], a, 0, 0, 0);
        a = __builtin_amdgcn_mfma_f32_16x16x32_bf16(xa, wihLo[c], a, 0, 0, 0);
      }
      xq = a;
    }

    // ---- barrier wait: 8 leader blocks poll root, fan out via group flags ----
    if (tid == 0){
      if (blockIdx.x < 8){
        while (__hip_atomic_load(&ctr2[t], __ATOMIC_ACQUIRE,
                                 __HIP_MEMORY_SCOPE_AGENT) != 8u)
          __builtin_amdgcn_s_sleep(1);
        __hip_atomic_store(&gflag[grp * T_ + t], 1u,
                           __ATOMIC_RELEASE, __HIP_MEMORY_SCOPE_AGENT);
      } else {
        while (__hip_atomic_load(&gflag[grp * T_ + t], __ATOMIC_ACQUIRE,
                                 __HIP_MEMORY_SCOPE_AGENT) == 0u)
          __builtin_amdgcn_s_sleep(2);
      }
    }
    __syncthreads();
    __threadfence();          // acquire: invalidate stale L1/L2 before reading h
  }
}

// ---------------------------------------------------------------------------
// Head: y1 = relu(hT @ fc1_w^T + b1);  out = y1 @ fc2_w^T + b2   (all fp32)
// ---------------------------------------------------------------------------
__global__ void fc1_kernel(const float* __restrict__ hT, const float* __restrict__ w1,
                           const float* __restrict__ b1, float* __restrict__ y1)
{
  int o = blockIdx.x * 256 + threadIdx.x;     // 0..65535
  int b = o >> 10, j = o & 1023;
  const float4* hp = (const float4*)(hT + (long)b * H_);
  const float4* wp = (const float4*)(w1 + (long)j * H_);
  float s = 0.f;
  #pragma unroll 4
  for (int k = 0; k < H_ / 4; k++){
    float4 hv = hp[k], wv = wp[k];
    s += hv.x * wv.x + hv.y * wv.y + hv.z * wv.z + hv.w * wv.w;
  }
  s += b1[j];
  y1[o] = s > 0.f ? s : 0.f;
}

__global__ void fc2_kernel(const float* __restrict__ y1, const float* __restrict__ w2,
                           const float* __restrict__ b2, float* __restrict__ out)
{
  __shared__ float ybuf[H_];
  int b = blockIdx.x;
  for (int k = threadIdx.x; k < H_; k += 256) ybuf[k] = y1[(long)b * H_ + k];
  __syncthreads();
  if (threadIdx.x < C_){
    const float* wp = w2 + (long)threadIdx.x * H_;
    float s = 0.f;
    for (int k = 0; k < H_; k++) s += ybuf[k] * wp[k];
    out[b * C_ + threadIdx.x] = s + b2[threadIdx.x];
  }
}

// ---------------------------------------------------------------------------
extern "C" void kernel_launch(void* const* d_in, const int* in_sizes, int n_in,
                              void* d_out, int out_size, void* d_ws, size_t ws_size,
                              hipStream_t stream)
{
  const float* x   = (const float*)d_in[0];
  const float* wih = (const float*)d_in[1];
  const float* whh = (const float*)d_in[2];
  const float* bih = (const float*)d_in[3];
  const float* bhh = (const float*)d_in[4];
  const float* w1  = (const float*)d_in[5];
  const float* b1  = (const float*)d_in[6];
  const float* w2  = (const float*)d_in[7];
  const float* b2  = (const float*)d_in[8];
  float* out = (float*)d_out;

  char* ws = (char*)d_ws;
  size_t off = 0;
  auto carve = [&](size_t bytes) -> char* {
    char* p = ws + off; off += (bytes + 255) & ~(size_t)255; return p;
  };
  short*    whhh = (short*)carve((size_t)H_ * H_ * 2);
  short*    whhl = (short*)carve((size_t)H_ * H_ * 2);
  short*    wihh = (short*)carve((size_t)H_ * E_ * 2);
  short*    wihl = (short*)carve((size_t)H_ * E_ * 2);
  short*    hb0  = (short*)carve((size_t)B_ * H_ * 2);
  short*    hb1  = (short*)carve((size_t)B_ * H_ * 2);
  float*    hT   = (float*)carve((size_t)B_ * H_ * 4);
  float*    y1   = (float*)carve((size_t)B_ * H_ * 4);
  unsigned* ctrs = (unsigned*)carve(17UL * T_ * 4);
  size_t xbytes = (size_t)B_ * T_ * E_ * 2;
  short* xb = (off + xbytes <= ws_size) ? (short*)carve(xbytes) : nullptr;

  prep_kernel<<<2048, 256, 0, stream>>>(x, wih, whh, whhh, whhl, wihh, wihl,
                                        hb0, ctrs, xb);
  rnn_scan<<<NBLK, 256, 0, stream>>>(x, xb, wihh, wihl, whhh, whhl,
                                     bih, bhh, hb0, hb1, hT, ctrs);
  fc1_kernel<<<256, 256, 0, stream>>>(hT, w1, b1, y1);
  fc2_kernel<<<64, 256, 0, stream>>>(y1, w2, b2, out);
}

// Round 2
// 3319.336 us; speedup vs baseline: 7.5558x; 7.5558x over previous
//
#include <hip/hip_runtime.h>

#define B_ 64
#define T_ 512
#define E_ 512
#define H_ 1024
#define C_ 20
#define NBLK 256

typedef __attribute__((ext_vector_type(8))) __bf16 bf16x8;
typedef __attribute__((ext_vector_type(4))) float f32x4;
typedef unsigned long long u64;

__device__ __forceinline__ short f2bf(float x){
  unsigned u = __float_as_uint(x);
  unsigned r = (u + 0x7fffu + ((u >> 16) & 1u)) >> 16;   // RNE
  return (short)r;
}
__device__ __forceinline__ float bf2f(short s){
  return __uint_as_float(((unsigned)(unsigned short)s) << 16);
}

// Relaxed agent-scope ops: compile to single sc1-flagged instructions that
// bypass L1/L2 and hit the (memory-side, device-coherent) Infinity Cache.
// No buffer_inv / buffer_wbl2 anywhere in the persistent loop.
__device__ __forceinline__ u64 ld_agent_u64(const u64* p){
  return __hip_atomic_load(p, __ATOMIC_RELAXED, __HIP_MEMORY_SCOPE_AGENT);
}
__device__ __forceinline__ void st_agent_u64(u64* p, u64 v){
  __hip_atomic_store(p, v, __ATOMIC_RELAXED, __HIP_MEMORY_SCOPE_AGENT);
}
__device__ __forceinline__ bf16x8 ld_h16(const short* p){
  union { u64 q[2]; bf16x8 v; } u;
  u.q[0] = ld_agent_u64((const u64*)p);
  u.q[1] = ld_agent_u64((const u64*)p + 1);
  return u.v;
}

// ---------------------------------------------------------------------------
// Prep: W -> hi/lo bf16 splits, x -> bf16, zero h0 + per-step barrier ctrs.
// Counters MUST be re-zeroed every launch (ws not re-poisoned between replays).
// ---------------------------------------------------------------------------
__global__ void prep_kernel(const float* __restrict__ x,
                            const float* __restrict__ wih,
                            const float* __restrict__ whh,
                            short* __restrict__ whhh, short* __restrict__ whhl,
                            short* __restrict__ wihh, short* __restrict__ wihl,
                            short* __restrict__ h0,
                            unsigned* __restrict__ ctrs,
                            short* __restrict__ xb)
{
  const long NH  = (long)H_ * H_;
  const long NI  = (long)H_ * E_;
  const long NH0 = (long)B_ * H_;
  const long NC  = T_;                       // one barrier counter per step
  const long NX  = xb ? (long)B_ * T_ * E_ : 0;
  const long TOT = NH + NI + NH0 + NC + NX;
  long i = (long)blockIdx.x * blockDim.x + threadIdx.x;
  const long stride = (long)gridDim.x * blockDim.x;
  for (; i < TOT; i += stride){
    if (i < NH){
      float v = whh[i]; short hi = f2bf(v);
      whhh[i] = hi; whhl[i] = f2bf(v - bf2f(hi));
    } else if (i < NH + NI){
      long j = i - NH; float v = wih[j]; short hi = f2bf(v);
      wihh[j] = hi; wihl[j] = f2bf(v - bf2f(hi));
    } else if (i < NH + NI + NH0){
      h0[i - NH - NI] = 0;
    } else if (i < NH + NI + NH0 + NC){
      ctrs[i - NH - NI - NH0] = 0u;
    } else {
      long j = i - NH - NI - NH0 - NC;
      xb[j] = f2bf(x[j]);
    }
  }
}

// ---------------------------------------------------------------------------
// Persistent scan. 256 blocks = 4 batch-groups x 64 col-groups; block tile
// C[16 x 16], K=1024 split over 4 waves. Weights pinned in VGPRs (hi+lo bf16).
// h exchanged through the Infinity Cache via relaxed agent atomics; one flat
// per-step counter barrier (relaxed add + relaxed polls, s_sleep backoff).
// Input projection for t+1 is computed between arrive and wait.
// ---------------------------------------------------------------------------
__global__ __launch_bounds__(256, 2) void rnn_scan(
    const float* __restrict__ x, const short* __restrict__ xb,
    const short* __restrict__ wihh, const short* __restrict__ wihl,
    const short* __restrict__ whhh, const short* __restrict__ whhl,
    const float* __restrict__ bih, const float* __restrict__ bhh,
    short* __restrict__ hb0, short* __restrict__ hb1,
    float* __restrict__ hT, unsigned* __restrict__ ctr)
{
  const int tid  = threadIdx.x;
  const int lane = tid & 63;
  const int wv   = tid >> 6;          // wave 0..3 -> K quarter
  const int bg   = blockIdx.x >> 6;   // batch group 0..3
  const int cg   = blockIdx.x & 63;   // col group 0..63
  const int r16  = lane & 15;
  const int kq   = lane >> 4;         // 0..3

  __shared__ float redbuf[4 * 256];
  __shared__ short hpack[256];

  const int colRow = cg * 16 + r16;   // output col == W row
  const int hrow   = bg * 16 + r16;   // batch row

  // --- weight fragments, loaded once then PINNED (opaque asm forbids reload) ---
  bf16x8 whhHi[8], whhLo[8];
  #pragma unroll
  for (int c = 0; c < 8; c++){
    int k0 = wv * 256 + c * 32 + kq * 8;
    whhHi[c] = *(const bf16x8*)(whhh + (long)colRow * H_ + k0);
    whhLo[c] = *(const bf16x8*)(whhl + (long)colRow * H_ + k0);
  }
  bf16x8 wihHi[4], wihLo[4];
  #pragma unroll
  for (int c = 0; c < 4; c++){
    int k0 = wv * 128 + c * 32 + kq * 8;
    wihHi[c] = *(const bf16x8*)(wihh + (long)colRow * E_ + k0);
    wihLo[c] = *(const bf16x8*)(wihl + (long)colRow * E_ + k0);
  }
  float bias = bih[colRow] + bhh[colRow];
  #pragma unroll
  for (int c = 0; c < 8; c++)
    asm volatile("" : "+v"(whhHi[c]), "+v"(whhLo[c]));
  #pragma unroll
  for (int c = 0; c < 4; c++)
    asm volatile("" : "+v"(wihHi[c]), "+v"(wihLo[c]));
  asm volatile("" : "+v"(bias));

  auto load_xa = [&](int tn, int c) -> bf16x8 {
    int k0 = wv * 128 + c * 32 + kq * 8;
    if (xb){
      return *(const bf16x8*)(xb + ((long)hrow * T_ + tn) * E_ + k0);
    } else {
      const float* xp = x + ((long)hrow * T_ + tn) * E_ + k0;
      float4 f0 = *(const float4*)xp;
      float4 f1 = *(const float4*)(xp + 4);
      union { short s[8]; bf16x8 v; } u;
      u.s[0]=f2bf(f0.x); u.s[1]=f2bf(f0.y); u.s[2]=f2bf(f0.z); u.s[3]=f2bf(f0.w);
      u.s[4]=f2bf(f1.x); u.s[5]=f2bf(f1.y); u.s[6]=f2bf(f1.z); u.s[7]=f2bf(f1.w);
      return u.v;
    }
  };

  // input projection for t=0 (wave 0 seeds the bias so it is added exactly once)
  f32x4 xq;
  {
    float b0 = (wv == 0) ? bias : 0.f;
    f32x4 a = { b0, b0, b0, b0 };
    #pragma unroll
    for (int c = 0; c < 4; c++){
      bf16x8 xa = load_xa(0, c);
      a = __builtin_amdgcn_mfma_f32_16x16x32_bf16(xa, wihHi[c], a, 0, 0, 0);
      a = __builtin_amdgcn_mfma_f32_16x16x32_bf16(xa, wihLo[c], a, 0, 0, 0);
    }
    xq = a;
  }

  for (int t = 0; t < T_; ++t){
    const short* hbr = (t & 1) ? hb1 : hb0;
    short*       hbw = (t & 1) ? hb0 : hb1;

    // ---- h fragments via agent (IC-coherent) loads ----
    bf16x8 ha[8];
    #pragma unroll
    for (int c = 0; c < 8; c++){
      int k0 = wv * 256 + c * 32 + kq * 8;
      ha[c] = ld_h16(hbr + (long)hrow * H_ + k0);
    }
    // ---- recurrent GEMM: acc = xq_t + h_t @ W_hh^T (this wave's K quarter) ----
    f32x4 acc = xq;
    #pragma unroll
    for (int c = 0; c < 8; c++){
      acc = __builtin_amdgcn_mfma_f32_16x16x32_bf16(ha[c], whhHi[c], acc, 0, 0, 0);
      acc = __builtin_amdgcn_mfma_f32_16x16x32_bf16(ha[c], whhLo[c], acc, 0, 0, 0);
    }

    // ---- cross-wave K-reduction in LDS; C-frag: col=lane&15, row=(lane>>4)*4+i ----
    #pragma unroll
    for (int i = 0; i < 4; i++)
      redbuf[wv * 256 + (kq * 4 + i) * 16 + r16] = acc[i];
    __syncthreads();
    {
      int row = tid >> 4, col = tid & 15;
      float s = redbuf[tid] + redbuf[256 + tid] + redbuf[512 + tid] + redbuf[768 + tid];
      float hv = tanhf(s);
      hpack[tid] = f2bf(hv);                            // [row16][col16] row-major
      if (t == T_ - 1) hT[(bg * 16 + row) * H_ + cg * 16 + col] = hv;
    }
    __syncthreads();
    if (t == T_ - 1) break;      // hT flushed at kernel end; no more consumers

    // ---- publish h: 64 lanes x 8B agent stores, then wait for ack ----
    if (tid < 64){
      u64 v = ((const u64*)hpack)[tid];
      st_agent_u64((u64*)(hbw + (long)(bg * 16 + (tid >> 2)) * H_ + cg * 16 + (tid & 3) * 4), v);
      asm volatile("s_waitcnt vmcnt(0)" ::: "memory");   // stores acked at coherent point
    }
    __syncthreads();

    // ---- barrier arrive: one relaxed atomic add on this step's counter ----
    if (tid == 0)
      __hip_atomic_fetch_add(&ctr[t], 1u, __ATOMIC_RELAXED, __HIP_MEMORY_SCOPE_AGENT);

    // ---- overlap: input projection for t+1 while the barrier settles ----
    {
      float b0 = (wv == 0) ? bias : 0.f;
      f32x4 a = { b0, b0, b0, b0 };
      #pragma unroll
      for (int c = 0; c < 4; c++){
        bf16x8 xa = load_xa(t + 1, c);
        a = __builtin_amdgcn_mfma_f32_16x16x32_bf16(xa, wihHi[c], a, 0, 0, 0);
        a = __builtin_amdgcn_mfma_f32_16x16x32_bf16(xa, wihLo[c], a, 0, 0, 0);
      }
      xq = a;
    }

    // ---- barrier wait: relaxed polls (no cache maintenance), s_sleep backoff ----
    if (tid == 0){
      while (__hip_atomic_load(&ctr[t], __ATOMIC_RELAXED,
                               __HIP_MEMORY_SCOPE_AGENT) != NBLK)
        __builtin_amdgcn_s_sleep(4);
    }
    __syncthreads();
  }
}

// ---------------------------------------------------------------------------
// Head: y1 = relu(hT @ fc1_w^T + b1);  out = y1 @ fc2_w^T + b2   (all fp32)
// ---------------------------------------------------------------------------
__global__ void fc1_kernel(const float* __restrict__ hT, const float* __restrict__ w1,
                           const float* __restrict__ b1, float* __restrict__ y1)
{
  int o = blockIdx.x * 256 + threadIdx.x;     // 0..65535
  int b = o >> 10, j = o & 1023;
  const float4* hp = (const float4*)(hT + (long)b * H_);
  const float4* wp = (const float4*)(w1 + (long)j * H_);
  float s = 0.f;
  #pragma unroll 4
  for (int k = 0; k < H_ / 4; k++){
    float4 hv = hp[k], wv = wp[k];
    s += hv.x * wv.x + hv.y * wv.y + hv.z * wv.z + hv.w * wv.w;
  }
  s += b1[j];
  y1[o] = s > 0.f ? s : 0.f;
}

__global__ void fc2_kernel(const float* __restrict__ y1, const float* __restrict__ w2,
                           const float* __restrict__ b2, float* __restrict__ out)
{
  __shared__ float ybuf[H_];
  int b = blockIdx.x;
  for (int k = threadIdx.x; k < H_; k += 256) ybuf[k] = y1[(long)b * H_ + k];
  __syncthreads();
  if (threadIdx.x < C_){
    const float* wp = w2 + (long)threadIdx.x * H_;
    float s = 0.f;
    for (int k = 0; k < H_; k++) s += ybuf[k] * wp[k];
    out[b * C_ + threadIdx.x] = s + b2[threadIdx.x];
  }
}

// ---------------------------------------------------------------------------
extern "C" void kernel_launch(void* const* d_in, const int* in_sizes, int n_in,
                              void* d_out, int out_size, void* d_ws, size_t ws_size,
                              hipStream_t stream)
{
  const float* x   = (const float*)d_in[0];
  const float* wih = (const float*)d_in[1];
  const float* whh = (const float*)d_in[2];
  const float* bih = (const float*)d_in[3];
  const float* bhh = (const float*)d_in[4];
  const float* w1  = (const float*)d_in[5];
  const float* b1  = (const float*)d_in[6];
  const float* w2  = (const float*)d_in[7];
  const float* b2  = (const float*)d_in[8];
  float* out = (float*)d_out;

  char* ws = (char*)d_ws;
  size_t off = 0;
  auto carve = [&](size_t bytes) -> char* {
    char* p = ws + off; off += (bytes + 255) & ~(size_t)255; return p;
  };
  short*    whhh = (short*)carve((size_t)H_ * H_ * 2);
  short*    whhl = (short*)carve((size_t)H_ * H_ * 2);
  short*    wihh = (short*)carve((size_t)H_ * E_ * 2);
  short*    wihl = (short*)carve((size_t)H_ * E_ * 2);
  short*    hb0  = (short*)carve((size_t)B_ * H_ * 2);
  short*    hb1  = (short*)carve((size_t)B_ * H_ * 2);
  float*    hT   = (float*)carve((size_t)B_ * H_ * 4);
  float*    y1   = (float*)carve((size_t)B_ * H_ * 4);
  unsigned* ctrs = (unsigned*)carve((size_t)T_ * 4);
  size_t xbytes = (size_t)B_ * T_ * E_ * 2;
  short* xb = (off + xbytes <= ws_size) ? (short*)carve(xbytes) : nullptr;

  prep_kernel<<<2048, 256, 0, stream>>>(x, wih, whh, whhh, whhl, wihh, wihl,
                                        hb0, ctrs, xb);
  rnn_scan<<<NBLK, 256, 0, stream>>>(x, xb, wihh, wihl, whhh, whhl,
                                     bih, bhh, hb0, hb1, hT, ctrs);
  fc1_kernel<<<256, 256, 0, stream>>>(hT, w1, b1, y1);
  fc2_kernel<<<64, 256, 0, stream>>>(y1, w2, b2, out);
}

// Round 3
// 2090.216 us; speedup vs baseline: 11.9989x; 1.5880x over previous
//
#include <hip/hip_runtime.h>

#define B_ 64
#define T_ 512
#define E_ 512
#define H_ 1024
#define C_ 20
#define NBLK 256

typedef __attribute__((ext_vector_type(8))) __bf16 bf16x8;
typedef __attribute__((ext_vector_type(4))) float f32x4;
typedef unsigned long long u64;

__device__ __forceinline__ short f2bf(float x){
  unsigned u = __float_as_uint(x);
  unsigned r = (u + 0x7fffu + ((u >> 16) & 1u)) >> 16;   // RNE
  return (short)r;
}
__device__ __forceinline__ float bf2f(short s){
  return __uint_as_float(((unsigned)(unsigned short)s) << 16);
}

// Relaxed agent-scope ops: single coherent-point instructions, no L2/L1
// cache-maintenance (no buffer_inv / buffer_wbl2) in the persistent loop.
__device__ __forceinline__ u64 ld_agent_u64(const u64* p){
  return __hip_atomic_load(p, __ATOMIC_RELAXED, __HIP_MEMORY_SCOPE_AGENT);
}
__device__ __forceinline__ void st_agent_u64(u64* p, u64 v){
  __hip_atomic_store(p, v, __ATOMIC_RELAXED, __HIP_MEMORY_SCOPE_AGENT);
}
__device__ __forceinline__ unsigned ld_agent_u32(const unsigned* p){
  return __hip_atomic_load(p, __ATOMIC_RELAXED, __HIP_MEMORY_SCOPE_AGENT);
}
__device__ __forceinline__ void st_agent_u32(unsigned* p, unsigned v){
  __hip_atomic_store(p, v, __ATOMIC_RELAXED, __HIP_MEMORY_SCOPE_AGENT);
}
__device__ __forceinline__ bf16x8 ld_h16(const short* p){
  union { u64 q[2]; bf16x8 v; } u;
  u.q[0] = ld_agent_u64((const u64*)p);
  u.q[1] = ld_agent_u64((const u64*)p + 1);
  return u.v;
}

// ---------------------------------------------------------------------------
// Prep: W -> hi/lo bf16 splits, x -> bf16, zero h0 + per-step barrier flags.
// Flags MUST be re-zeroed every launch (ws not re-poisoned between replays).
// ---------------------------------------------------------------------------
__global__ void prep_kernel(const float* __restrict__ x,
                            const float* __restrict__ wih,
                            const float* __restrict__ whh,
                            short* __restrict__ whhh, short* __restrict__ whhl,
                            short* __restrict__ wihh, short* __restrict__ wihl,
                            short* __restrict__ h0,
                            unsigned* __restrict__ flags,
                            short* __restrict__ xb)
{
  const long NH  = (long)H_ * H_;
  const long NI  = (long)H_ * E_;
  const long NH0 = (long)B_ * H_;
  const long NC  = 4L * 64 * T_;             // flags[t][bg][cg]
  const long NX  = xb ? (long)B_ * T_ * E_ : 0;
  const long TOT = NH + NI + NH0 + NC + NX;
  long i = (long)blockIdx.x * blockDim.x + threadIdx.x;
  const long stride = (long)gridDim.x * blockDim.x;
  for (; i < TOT; i += stride){
    if (i < NH){
      float v = whh[i]; short hi = f2bf(v);
      whhh[i] = hi; whhl[i] = f2bf(v - bf2f(hi));
    } else if (i < NH + NI){
      long j = i - NH; float v = wih[j]; short hi = f2bf(v);
      wihh[j] = hi; wihl[j] = f2bf(v - bf2f(hi));
    } else if (i < NH + NI + NH0){
      h0[i - NH - NI] = 0;
    } else if (i < NH + NI + NH0 + NC){
      flags[i - NH - NI - NH0] = 0u;
    } else {
      long j = i - NH - NI - NH0 - NC;
      xb[j] = f2bf(x[j]);
    }
  }
}

// ---------------------------------------------------------------------------
// Persistent scan. 256 blocks = 4 batch-groups x 64 col-groups; block tile
// C[16 x 16], K=1024 split over 4 waves. Weights pinned in regs (hi+lo bf16).
// h exchanged via relaxed agent (coherent-point) loads/stores. Barrier is
// ATOMIC-FREE: per-step per-bg flag slot per block (contention-free stores),
// consumers poll their bg's 64 flags with one 64-lane load + __all. A block
// only waits on the 64 blocks of its OWN batch-group.
// ---------------------------------------------------------------------------
__global__ __launch_bounds__(256, 2) void rnn_scan(
    const float* __restrict__ x, const short* __restrict__ xb,
    const short* __restrict__ wihh, const short* __restrict__ wihl,
    const short* __restrict__ whhh, const short* __restrict__ whhl,
    const float* __restrict__ bih, const float* __restrict__ bhh,
    short* __restrict__ hb0, short* __restrict__ hb1,
    float* __restrict__ hT, unsigned* __restrict__ flags)
{
  const int tid  = threadIdx.x;
  const int lane = tid & 63;
  const int wv   = tid >> 6;          // wave 0..3 -> K quarter
  const int bg   = blockIdx.x >> 6;   // batch group 0..3
  const int cg   = blockIdx.x & 63;   // col group 0..63
  const int r16  = lane & 15;
  const int kq   = lane >> 4;         // 0..3

  __shared__ float redbuf[4 * 256];
  __shared__ short hpack[256];

  const int colRow = cg * 16 + r16;   // output col == W row
  const int hrow   = bg * 16 + r16;   // batch row

  // --- weight fragments, loaded once then PINNED (opaque asm forbids reload) ---
  bf16x8 whhHi[8], whhLo[8];
  #pragma unroll
  for (int c = 0; c < 8; c++){
    int k0 = wv * 256 + c * 32 + kq * 8;
    whhHi[c] = *(const bf16x8*)(whhh + (long)colRow * H_ + k0);
    whhLo[c] = *(const bf16x8*)(whhl + (long)colRow * H_ + k0);
  }
  bf16x8 wihHi[4], wihLo[4];
  #pragma unroll
  for (int c = 0; c < 4; c++){
    int k0 = wv * 128 + c * 32 + kq * 8;
    wihHi[c] = *(const bf16x8*)(wihh + (long)colRow * E_ + k0);
    wihLo[c] = *(const bf16x8*)(wihl + (long)colRow * E_ + k0);
  }
  float bias = bih[colRow] + bhh[colRow];
  #pragma unroll
  for (int c = 0; c < 8; c++)
    asm volatile("" : "+v"(whhHi[c]), "+v"(whhLo[c]));
  #pragma unroll
  for (int c = 0; c < 4; c++)
    asm volatile("" : "+v"(wihHi[c]), "+v"(wihLo[c]));
  asm volatile("" : "+v"(bias));

  auto load_xa = [&](int tn, int c) -> bf16x8 {
    int k0 = wv * 128 + c * 32 + kq * 8;
    if (xb){
      return *(const bf16x8*)(xb + ((long)hrow * T_ + tn) * E_ + k0);
    } else {
      const float* xp = x + ((long)hrow * T_ + tn) * E_ + k0;
      float4 f0 = *(const float4*)xp;
      float4 f1 = *(const float4*)(xp + 4);
      union { short s[8]; bf16x8 v; } u;
      u.s[0]=f2bf(f0.x); u.s[1]=f2bf(f0.y); u.s[2]=f2bf(f0.z); u.s[3]=f2bf(f0.w);
      u.s[4]=f2bf(f1.x); u.s[5]=f2bf(f1.y); u.s[6]=f2bf(f1.z); u.s[7]=f2bf(f1.w);
      return u.v;
    }
  };

  // input projection for t=0 (wave 0 seeds the bias; two independent chains)
  f32x4 xq;
  {
    float b0 = (wv == 0) ? bias : 0.f;
    f32x4 aH = { b0, b0, b0, b0 };
    f32x4 aL = { 0.f, 0.f, 0.f, 0.f };
    #pragma unroll
    for (int c = 0; c < 4; c++){
      bf16x8 xa = load_xa(0, c);
      aH = __builtin_amdgcn_mfma_f32_16x16x32_bf16(xa, wihHi[c], aH, 0, 0, 0);
      aL = __builtin_amdgcn_mfma_f32_16x16x32_bf16(xa, wihLo[c], aL, 0, 0, 0);
    }
    xq = aH + aL;
  }

  for (int t = 0; t < T_; ++t){
    const short* hbr = (t & 1) ? hb1 : hb0;
    short*       hbw = (t & 1) ? hb0 : hb1;

    // ---- h fragments via agent (coherent-point) loads ----
    bf16x8 ha[8];
    #pragma unroll
    for (int c = 0; c < 8; c++){
      int k0 = wv * 256 + c * 32 + kq * 8;
      ha[c] = ld_h16(hbr + (long)hrow * H_ + k0);
    }
    // ---- recurrent GEMM, two independent accumulator chains (hi / lo) ----
    f32x4 accH = xq;
    f32x4 accL = { 0.f, 0.f, 0.f, 0.f };
    #pragma unroll
    for (int c = 0; c < 8; c++){
      accH = __builtin_amdgcn_mfma_f32_16x16x32_bf16(ha[c], whhHi[c], accH, 0, 0, 0);
      accL = __builtin_amdgcn_mfma_f32_16x16x32_bf16(ha[c], whhLo[c], accL, 0, 0, 0);
    }
    f32x4 acc = accH + accL;

    // ---- cross-wave K-reduction in LDS; C-frag: col=lane&15, row=(lane>>4)*4+i ----
    #pragma unroll
    for (int i = 0; i < 4; i++)
      redbuf[wv * 256 + (kq * 4 + i) * 16 + r16] = acc[i];
    __syncthreads();
    {
      int row = tid >> 4, col = tid & 15;
      float s = redbuf[tid] + redbuf[256 + tid] + redbuf[512 + tid] + redbuf[768 + tid];
      float hv = tanhf(s);
      hpack[tid] = f2bf(hv);                            // [row16][col16] row-major
      if (t == T_ - 1) hT[(bg * 16 + row) * H_ + cg * 16 + col] = hv;
    }
    __syncthreads();
    if (t == T_ - 1) break;      // hT flushed at kernel end; no more consumers

    // ---- publish h (wave 0: 64 x 8B stores), ack, then set our flag ----
    if (tid < 64){
      u64 v = ((const u64*)hpack)[tid];
      st_agent_u64((u64*)(hbw + (long)(bg * 16 + (tid >> 2)) * H_ + cg * 16 + (tid & 3) * 4), v);
      asm volatile("s_waitcnt vmcnt(0)" ::: "memory");   // wave-0 stores acked
      if (tid == 0)
        st_agent_u32(&flags[(((unsigned)t * 4 + bg) << 6) + cg], 1u);
    }

    // ---- overlap: input projection for t+1 while flags propagate ----
    {
      float b0 = (wv == 0) ? bias : 0.f;
      f32x4 aH = { b0, b0, b0, b0 };
      f32x4 aL = { 0.f, 0.f, 0.f, 0.f };
      #pragma unroll
      for (int c = 0; c < 4; c++){
        bf16x8 xa = load_xa(t + 1, c);
        aH = __builtin_amdgcn_mfma_f32_16x16x32_bf16(xa, wihHi[c], aH, 0, 0, 0);
        aL = __builtin_amdgcn_mfma_f32_16x16x32_bf16(xa, wihLo[c], aL, 0, 0, 0);
      }
      xq = aH + aL;
    }

    // ---- barrier wait: wave 0 polls its bg's 64 flags (one 64-lane load) ----
    if (wv == 0){
      const unsigned* fp = flags + (((unsigned)t * 4 + bg) << 6) + lane;
      unsigned v;
      do {
        v = ld_agent_u32(fp);
      } while (!__all(v != 0u));
    }
    __syncthreads();
  }
}

// ---------------------------------------------------------------------------
// Head: y1 = relu(hT @ fc1_w^T + b1);  out = y1 @ fc2_w^T + b2   (all fp32)
// ---------------------------------------------------------------------------
__global__ void fc1_kernel(const float* __restrict__ hT, const float* __restrict__ w1,
                           const float* __restrict__ b1, float* __restrict__ y1)
{
  int o = blockIdx.x * 256 + threadIdx.x;     // 0..65535
  int b = o >> 10, j = o & 1023;
  const float4* hp = (const float4*)(hT + (long)b * H_);
  const float4* wp = (const float4*)(w1 + (long)j * H_);
  float s = 0.f;
  #pragma unroll 4
  for (int k = 0; k < H_ / 4; k++){
    float4 hv = hp[k], wv = wp[k];
    s += hv.x * wv.x + hv.y * wv.y + hv.z * wv.z + hv.w * wv.w;
  }
  s += b1[j];
  y1[o] = s > 0.f ? s : 0.f;
}

__global__ void fc2_kernel(const float* __restrict__ y1, const float* __restrict__ w2,
                           const float* __restrict__ b2, float* __restrict__ out)
{
  __shared__ float ybuf[H_];
  int b = blockIdx.x;
  for (int k = threadIdx.x; k < H_; k += 256) ybuf[k] = y1[(long)b * H_ + k];
  __syncthreads();
  if (threadIdx.x < C_){
    const float* wp = w2 + (long)threadIdx.x * H_;
    float s = 0.f;
    for (int k = 0; k < H_; k++) s += ybuf[k] * wp[k];
    out[b * C_ + threadIdx.x] = s + b2[threadIdx.x];
  }
}

// ---------------------------------------------------------------------------
extern "C" void kernel_launch(void* const* d_in, const int* in_sizes, int n_in,
                              void* d_out, int out_size, void* d_ws, size_t ws_size,
                              hipStream_t stream)
{
  const float* x   = (const float*)d_in[0];
  const float* wih = (const float*)d_in[1];
  const float* whh = (const float*)d_in[2];
  const float* bih = (const float*)d_in[3];
  const float* bhh = (const float*)d_in[4];
  const float* w1  = (const float*)d_in[5];
  const float* b1  = (const float*)d_in[6];
  const float* w2  = (const float*)d_in[7];
  const float* b2  = (const float*)d_in[8];
  float* out = (float*)d_out;

  char* ws = (char*)d_ws;
  size_t off = 0;
  auto carve = [&](size_t bytes) -> char* {
    char* p = ws + off; off += (bytes + 255) & ~(size_t)255; return p;
  };
  short*    whhh = (short*)carve((size_t)H_ * H_ * 2);
  short*    whhl = (short*)carve((size_t)H_ * H_ * 2);
  short*    wihh = (short*)carve((size_t)H_ * E_ * 2);
  short*    wihl = (short*)carve((size_t)H_ * E_ * 2);
  short*    hb0  = (short*)carve((size_t)B_ * H_ * 2);
  short*    hb1  = (short*)carve((size_t)B_ * H_ * 2);
  float*    hT   = (float*)carve((size_t)B_ * H_ * 4);
  float*    y1   = (float*)carve((size_t)B_ * H_ * 4);
  unsigned* flags = (unsigned*)carve(4UL * 64 * T_ * 4);
  size_t xbytes = (size_t)B_ * T_ * E_ * 2;
  short* xb = (off + xbytes <= ws_size) ? (short*)carve(xbytes) : nullptr;

  prep_kernel<<<2048, 256, 0, stream>>>(x, wih, whh, whhh, whhl, wihh, wihl,
                                        hb0, flags, xb);
  rnn_scan<<<NBLK, 256, 0, stream>>>(x, xb, wihh, wihl, whhh, whhl,
                                     bih, bhh, hb0, hb1, hT, flags);
  fc1_kernel<<<256, 256, 0, stream>>>(hT, w1, b1, y1);
  fc2_kernel<<<64, 256, 0, stream>>>(y1, w2, b2, out);
}

// Round 4
// 2021.140 us; speedup vs baseline: 12.4090x; 1.0342x over previous
//
#include <hip/hip_runtime.h>

#define B_ 64
#define T_ 512
#define E_ 512
#define H_ 1024
#define C_ 20
#define NBLK 256
#define RING 16
#define BH (B_ * H_)

typedef __attribute__((ext_vector_type(8))) __bf16 bf16x8;
typedef __attribute__((ext_vector_type(4))) float f32x4;
typedef unsigned long long u64;

__device__ __forceinline__ short f2bf(float x){
  unsigned u = __float_as_uint(x);
  unsigned r = (u + 0x7fffu + ((u >> 16) & 1u)) >> 16;   // RNE
  return (short)r;
}
__device__ __forceinline__ float bf2f(short s){
  return __uint_as_float(((unsigned)(unsigned short)s) << 16);
}

// Relaxed agent-scope ops: single coherent-point (IC) instructions; no
// buffer_inv / buffer_wbl2 anywhere in the persistent loop.
__device__ __forceinline__ u64 ld_agent_u64(const u64* p){
  return __hip_atomic_load(p, __ATOMIC_RELAXED, __HIP_MEMORY_SCOPE_AGENT);
}
__device__ __forceinline__ void st_agent_u64(u64* p, u64 v){
  __hip_atomic_store(p, v, __ATOMIC_RELAXED, __HIP_MEMORY_SCOPE_AGENT);
}

// ---------------------------------------------------------------------------
// Prep: W -> hi/lo bf16 splits, x -> bf16, init h-ring (slot0 = h0 = zeros,
// slots 1..15 = 0xFFFF sentinel). Ring MUST be re-inited every launch (ws is
// not re-poisoned between graph replays).
// ---------------------------------------------------------------------------
__global__ void prep_kernel(const float* __restrict__ x,
                            const float* __restrict__ wih,
                            const float* __restrict__ whh,
                            short* __restrict__ whhh, short* __restrict__ whhl,
                            short* __restrict__ wihh, short* __restrict__ wihl,
                            short* __restrict__ hring,
                            short* __restrict__ xb)
{
  const long NH = (long)H_ * H_;
  const long NI = (long)H_ * E_;
  const long NR = (long)RING * BH;
  const long NX = xb ? (long)B_ * T_ * E_ : 0;
  const long TOT = NH + NI + NR + NX;
  long i = (long)blockIdx.x * blockDim.x + threadIdx.x;
  const long stride = (long)gridDim.x * blockDim.x;
  for (; i < TOT; i += stride){
    if (i < NH){
      float v = whh[i]; short hi = f2bf(v);
      whhh[i] = hi; whhl[i] = f2bf(v - bf2f(hi));
    } else if (i < NH + NI){
      long j = i - NH; float v = wih[j]; short hi = f2bf(v);
      wihh[j] = hi; wihl[j] = f2bf(v - bf2f(hi));
    } else if (i < NH + NI + NR){
      long j = i - NH - NI;
      hring[j] = (j < BH) ? (short)0 : (short)0xFFFF;   // h0 zeros, rest sentinel
    } else {
      long j = i - NH - NI - NR;
      xb[j] = f2bf(x[j]);
    }
  }
}

// ---------------------------------------------------------------------------
// Persistent scan. 256 blocks = 4 batch-groups x 64 col-groups; block tile
// C[16 x 16], K=1024 split over 4 waves. Weights pinned in regs (hi+lo bf16).
//
// Exchange protocol (no flags, no atomic RMW, no device fences):
//  - h[t] lives in hring slot t%16; consumers poll the DATA, validated by a
//    sentinel (0xFFFF = bf16 NaN pattern, never produced by tanh; 8B store
//    granules are single-copy atomic -> entirely sentinel or entirely fresh).
//  - Dataflow bounds skew to <=1 step inside a bg (step t needs ALL bg
//    producers' h[t]), so during step t the producer re-sentinels its region
//    of slot (t+8)%16 (holds h[t-8], reads provably complete). One
//    s_waitcnt vmcnt(0) orders reset-commit before the fresh publish at the
//    IC, so no consumer can mistake stale h[t-8] for future h[t+8].
//  - One __syncthreads per step (LDS reduce, double-buffered by t parity).
// ---------------------------------------------------------------------------
__global__ __launch_bounds__(256, 2) void rnn_scan(
    const float* __restrict__ x, const short* __restrict__ xb,
    const short* __restrict__ wihh, const short* __restrict__ wihl,
    const short* __restrict__ whhh, const short* __restrict__ whhl,
    const float* __restrict__ bih, const float* __restrict__ bhh,
    short* __restrict__ hring, float* __restrict__ hT)
{
  const int tid  = threadIdx.x;
  const int lane = tid & 63;
  const int wv   = tid >> 6;          // wave 0..3 -> K quarter
  const int bg   = blockIdx.x >> 6;   // batch group 0..3
  const int cg   = blockIdx.x & 63;   // col group 0..63
  const int r16  = lane & 15;
  const int kq   = lane >> 4;         // 0..3

  __shared__ float redbuf[2][1024];

  const int colRow = cg * 16 + r16;   // output col == W row
  const int hrow   = bg * 16 + r16;   // batch row

  // --- weight fragments, loaded once then pinned (compiler parks in AGPRs) ---
  bf16x8 whhHi[8], whhLo[8];
  #pragma unroll
  for (int c = 0; c < 8; c++){
    int k0 = wv * 256 + c * 32 + kq * 8;
    whhHi[c] = *(const bf16x8*)(whhh + (long)colRow * H_ + k0);
    whhLo[c] = *(const bf16x8*)(whhl + (long)colRow * H_ + k0);
  }
  bf16x8 wihHi[4], wihLo[4];
  #pragma unroll
  for (int c = 0; c < 4; c++){
    int k0 = wv * 128 + c * 32 + kq * 8;
    wihHi[c] = *(const bf16x8*)(wihh + (long)colRow * E_ + k0);
    wihLo[c] = *(const bf16x8*)(wihl + (long)colRow * E_ + k0);
  }
  float bias = bih[colRow] + bhh[colRow];
  #pragma unroll
  for (int c = 0; c < 8; c++)
    asm volatile("" : "+v"(whhHi[c]), "+v"(whhLo[c]));
  #pragma unroll
  for (int c = 0; c < 4; c++)
    asm volatile("" : "+v"(wihHi[c]), "+v"(wihLo[c]));
  asm volatile("" : "+v"(bias));

  // consumer fragment offset: + c*32 + slot*BH
  const int haOff  = hrow * H_ + wv * 256 + kq * 8;
  // producer 8B-granule offset (wave-0 lanes): row = lane>>2, cols (lane&3)*4..+4
  const int pubOff = (bg * 16 + (lane >> 2)) * H_ + cg * 16 + (lane & 3) * 4;

  auto load_xa = [&](int tn, int c) -> bf16x8 {
    int k0 = wv * 128 + c * 32 + kq * 8;
    if (xb){
      return *(const bf16x8*)(xb + ((long)hrow * T_ + tn) * E_ + k0);
    } else {
      const float* xp = x + ((long)hrow * T_ + tn) * E_ + k0;
      float4 f0 = *(const float4*)xp;
      float4 f1 = *(const float4*)(xp + 4);
      union { short s[8]; bf16x8 v; } u;
      u.s[0]=f2bf(f0.x); u.s[1]=f2bf(f0.y); u.s[2]=f2bf(f0.z); u.s[3]=f2bf(f0.w);
      u.s[4]=f2bf(f1.x); u.s[5]=f2bf(f1.y); u.s[6]=f2bf(f1.z); u.s[7]=f2bf(f1.w);
      return u.v;
    }
  };

  // input projection for t=0 (wave 0 seeds the bias; two independent chains)
  f32x4 xq;
  {
    float b0 = (wv == 0) ? bias : 0.f;
    f32x4 aH = { b0, b0, b0, b0 };
    f32x4 aL = { 0.f, 0.f, 0.f, 0.f };
    #pragma unroll
    for (int c = 0; c < 4; c++){
      bf16x8 xa = load_xa(0, c);
      aH = __builtin_amdgcn_mfma_f32_16x16x32_bf16(xa, wihHi[c], aH, 0, 0, 0);
      aL = __builtin_amdgcn_mfma_f32_16x16x32_bf16(xa, wihLo[c], aL, 0, 0, 0);
    }
    xq = aH + aL;
  }

  for (int t = 0; t < T_; ++t){
    const short* hb = hring + (long)(t & (RING - 1)) * BH + haOff;

    // ---- poll + load h fragments (sentinel-validated, detect==fetch) ----
    bf16x8 ha[8];
    unsigned need = 0xFFu;
    do {
      u64 q0[8], q1[8];
      #pragma unroll
      for (int c = 0; c < 8; c++){
        if (need & (1u << c)){
          q0[c] = ld_agent_u64((const u64*)(hb + c * 32));
          q1[c] = ld_agent_u64((const u64*)(hb + c * 32) + 1);
        }
      }
      #pragma unroll
      for (int c = 0; c < 8; c++){
        if (need & (1u << c)){
          bool bad = (((unsigned)q0[c] & 0xFFFFu) == 0xFFFFu) ||
                     (((unsigned)q1[c] & 0xFFFFu) == 0xFFFFu);
          if (!__any(bad)){
            union { u64 q[2]; bf16x8 v; } u;
            u.q[0] = q0[c]; u.q[1] = q1[c];
            ha[c] = u.v;
            need &= ~(1u << c);
          }
        }
      }
    } while (need);

    // ---- early re-sentinel of slot (t+8): holds h[t-8], reads provably done
    //      (we observed everyone's h[t] => everyone finished step t-1) ----
    if (wv == 0 && t + 8 < T_)
      st_agent_u64((u64*)(hring + (long)((t + 8) & (RING - 1)) * BH + pubOff),
                   0xFFFFFFFFFFFFFFFFull);

    // ---- recurrent GEMM, two independent accumulator chains (hi / lo) ----
    f32x4 accH = xq;
    f32x4 accL = { 0.f, 0.f, 0.f, 0.f };
    #pragma unroll
    for (int c = 0; c < 8; c++){
      accH = __builtin_amdgcn_mfma_f32_16x16x32_bf16(ha[c], whhHi[c], accH, 0, 0, 0);
      accL = __builtin_amdgcn_mfma_f32_16x16x32_bf16(ha[c], whhLo[c], accL, 0, 0, 0);
    }
    f32x4 acc = accH + accL;

    // ---- K-partials to LDS (double-buffered by t parity), one barrier ----
    float* rb = redbuf[t & 1];
    #pragma unroll
    for (int i = 0; i < 4; i++)
      rb[wv * 256 + (kq * 4 + i) * 16 + r16] = acc[i];
    __syncthreads();

    // ---- wave 0: reduce + tanh + publish; waves 1-3 run ahead ----
    if (wv == 0){
      const int e = (lane >> 2) * 16 + (lane & 3) * 4;   // row*16 + col0
      f32x4 s = *(const f32x4*)&rb[e];
      s += *(const f32x4*)&rb[256 + e];
      s += *(const f32x4*)&rb[512 + e];
      s += *(const f32x4*)&rb[768 + e];
      float hv[4];
      #pragma unroll
      for (int j = 0; j < 4; j++){
        float a  = fabsf(s[j]);
        float ex = __expf(-2.f * a);
        float r  = (1.f - ex) / (1.f + ex);
        hv[j] = copysignf(r, s[j]);
      }
      if (t < T_ - 1){
        u64 pk =  (u64)(unsigned short)f2bf(hv[0])
               | ((u64)(unsigned short)f2bf(hv[1]) << 16)
               | ((u64)(unsigned short)f2bf(hv[2]) << 32)
               | ((u64)(unsigned short)f2bf(hv[3]) << 48);
        asm volatile("s_waitcnt vmcnt(0)" ::: "memory");  // reset commits first
        st_agent_u64((u64*)(hring + (long)((t + 1) & (RING - 1)) * BH + pubOff), pk);
      } else {
        #pragma unroll
        for (int j = 0; j < 4; j++)
          hT[pubOff + j] = hv[j];
      }
    }

    // ---- overlapped input projection for t+1 ----
    if (t < T_ - 1){
      float b0 = (wv == 0) ? bias : 0.f;
      f32x4 aH = { b0, b0, b0, b0 };
      f32x4 aL = { 0.f, 0.f, 0.f, 0.f };
      #pragma unroll
      for (int c = 0; c < 4; c++){
        bf16x8 xa = load_xa(t + 1, c);
        aH = __builtin_amdgcn_mfma_f32_16x16x32_bf16(xa, wihHi[c], aH, 0, 0, 0);
        aL = __builtin_amdgcn_mfma_f32_16x16x32_bf16(xa, wihLo[c], aL, 0, 0, 0);
      }
      xq = aH + aL;
    }
  }
}

// ---------------------------------------------------------------------------
// Head: y1 = relu(hT @ fc1_w^T + b1);  out = y1 @ fc2_w^T + b2   (all fp32)
// ---------------------------------------------------------------------------
__global__ void fc1_kernel(const float* __restrict__ hT, const float* __restrict__ w1,
                           const float* __restrict__ b1, float* __restrict__ y1)
{
  int o = blockIdx.x * 256 + threadIdx.x;     // 0..65535
  int b = o >> 10, j = o & 1023;
  const float4* hp = (const float4*)(hT + (long)b * H_);
  const float4* wp = (const float4*)(w1 + (long)j * H_);
  float s = 0.f;
  #pragma unroll 4
  for (int k = 0; k < H_ / 4; k++){
    float4 hv = hp[k], wv = wp[k];
    s += hv.x * wv.x + hv.y * wv.y + hv.z * wv.z + hv.w * wv.w;
  }
  s += b1[j];
  y1[o] = s > 0.f ? s : 0.f;
}

__global__ void fc2_kernel(const float* __restrict__ y1, const float* __restrict__ w2,
                           const float* __restrict__ b2, float* __restrict__ out)
{
  __shared__ float ybuf[H_];
  int b = blockIdx.x;
  for (int k = threadIdx.x; k < H_; k += 256) ybuf[k] = y1[(long)b * H_ + k];
  __syncthreads();
  if (threadIdx.x < C_){
    const float* wp = w2 + (long)threadIdx.x * H_;
    float s = 0.f;
    for (int k = 0; k < H_; k++) s += ybuf[k] * wp[k];
    out[b * C_ + threadIdx.x] = s + b2[threadIdx.x];
  }
}

// ---------------------------------------------------------------------------
extern "C" void kernel_launch(void* const* d_in, const int* in_sizes, int n_in,
                              void* d_out, int out_size, void* d_ws, size_t ws_size,
                              hipStream_t stream)
{
  const float* x   = (const float*)d_in[0];
  const float* wih = (const float*)d_in[1];
  const float* whh = (const float*)d_in[2];
  const float* bih = (const float*)d_in[3];
  const float* bhh = (const float*)d_in[4];
  const float* w1  = (const float*)d_in[5];
  const float* b1  = (const float*)d_in[6];
  const float* w2  = (const float*)d_in[7];
  const float* b2  = (const float*)d_in[8];
  float* out = (float*)d_out;

  char* ws = (char*)d_ws;
  size_t off = 0;
  auto carve = [&](size_t bytes) -> char* {
    char* p = ws + off; off += (bytes + 255) & ~(size_t)255; return p;
  };
  short*  whhh  = (short*)carve((size_t)H_ * H_ * 2);
  short*  whhl  = (short*)carve((size_t)H_ * H_ * 2);
  short*  wihh  = (short*)carve((size_t)H_ * E_ * 2);
  short*  wihl  = (short*)carve((size_t)H_ * E_ * 2);
  short*  hring = (short*)carve((size_t)RING * BH * 2);
  float*  hT    = (float*)carve((size_t)B_ * H_ * 4);
  float*  y1    = (float*)carve((size_t)B_ * H_ * 4);
  size_t xbytes = (size_t)B_ * T_ * E_ * 2;
  short* xb = (off + xbytes <= ws_size) ? (short*)carve(xbytes) : nullptr;

  prep_kernel<<<2048, 256, 0, stream>>>(x, wih, whh, whhh, whhl, wihh, wihl,
                                        hring, xb);
  rnn_scan<<<NBLK, 256, 0, stream>>>(x, xb, wihh, wihl, whhh, whhl,
                                     bih, bhh, hring, hT);
  fc1_kernel<<<256, 256, 0, stream>>>(hT, w1, b1, y1);
  fc2_kernel<<<64, 256, 0, stream>>>(y1, w2, b2, out);
}